// Round 1
// baseline (6849.056 us; speedup 1.0000x reference)
//
#include <hip/hip_runtime.h>

#define NEG 0.01f
#define EPSQ 1e-5f

struct GnnArgs {
  const float* x;        // [B,50,64]
  const float* w;        // [B,50]
  const int*   src;      // [B,500]
  const int*   dst;      // [B,500]
  const float* W[3];     // [64,256],[256,256],[256,256]
  const float* ar[4];    // [50] each
  const float* gamma[3]; // [256]
  const float* beta[3];  // [256]
  const float* alpha[3]; // [256]
  const float* rW1[3];   // [256,128]
  const float* rb1[3];   // [128]
  const float* rW2[3];   // [128,64]
  const float* rb2[3];   // [64]
};

__device__ __forceinline__ float lrelu(float v) { return v > 0.f ? v : NEG * v; }

// C[50,256] = A[50,K] @ W[K,256], then scale row r by outs_[r], write into h.
// Thread layout: lane=t&63, jg=(t>>6)&1 (column pair-group), half=t>>7 (row half).
// Each thread: cols {lane+128*jg, lane+128*jg+64}, rows half*25..half*25+24.
template <int K>
__device__ __forceinline__ void conv_matmul(const float* __restrict__ A,
                                            const float* __restrict__ W,
                                            float* __restrict__ h,
                                            const float* __restrict__ outs_,
                                            int lane, int jg, int half) {
  constexpr int AS = (K == 64) ? 64 : 256;  // A row stride
  const int c0 = lane + 128 * jg;
  const int r0 = half * 25;
  float acc0[25], acc1[25];
#pragma unroll
  for (int i = 0; i < 25; i++) { acc0[i] = 0.f; acc1[i] = 0.f; }

  // software-pipelined W prefetch (hide L2 latency at low occupancy)
  float wa[4], wb[4];
  {
    const float* Wp = W + c0;
#pragma unroll
    for (int j = 0; j < 4; j++) { wa[j] = Wp[j * 256]; wb[j] = Wp[j * 256 + 64]; }
  }
  for (int kt = 0; kt < K / 4; ++kt) {
    const int k = kt * 4;
    const int kn = (kt + 1 < K / 4) ? (k + 4) : k;  // last iter: redundant reload
    float na[4], nb[4];
    {
      const float* Wn = W + kn * 256 + c0;
#pragma unroll
      for (int j = 0; j < 4; j++) { na[j] = Wn[j * 256]; nb[j] = Wn[j * 256 + 64]; }
    }
#pragma unroll
    for (int i = 0; i < 25; i++) {
      float4 av = *(const float4*)(A + (r0 + i) * AS + k);  // broadcast ds_read_b128
      acc0[i] += av.x * wa[0] + av.y * wa[1] + av.z * wa[2] + av.w * wa[3];
      acc1[i] += av.x * wb[0] + av.y * wb[1] + av.z * wb[2] + av.w * wb[3];
    }
#pragma unroll
    for (int j = 0; j < 4; j++) { wa[j] = na[j]; wb[j] = nb[j]; }
  }
  __syncthreads();  // all reads of A done before overwriting h (A may alias h)
#pragma unroll
  for (int i = 0; i < 25; i++) {
    float sc = outs_[r0 + i];  // out_deg^-0.5 (pre-scatter scaling)
    h[(r0 + i) * 256 + c0] = acc0[i] * sc;
    h[(r0 + i) * 256 + c0 + 64] = acc1[i] * sc;
  }
  __syncthreads();
}

// scatter(SpMM) + in-deg scale + GraphNorm + lrelu + weighted-mean + readout MLP
__device__ __forceinline__ void post_conv(
    float* __restrict__ h, float* __restrict__ sbuf,
    const unsigned short* __restrict__ epack, const float* __restrict__ ins_,
    const float* __restrict__ w_lds, float* __restrict__ war,
    float* __restrict__ red, const float* __restrict__ ar_next,
    const float* __restrict__ gamma, const float* __restrict__ beta,
    const float* __restrict__ alpha, const float* __restrict__ rW1,
    const float* __restrict__ rb1, const float* __restrict__ rW2,
    const float* __restrict__ rb2, float* __restrict__ out, int b, int ro_off,
    int t, int lane, int jg, int half) {
  // ---- scatter-add over edges, chunked 4 x 64 channels (agg fits sbuf) ----
  for (int ch = 0; ch < 4; ++ch) {
    for (int i = t; i < 3200; i += 256) sbuf[i] = 0.f;
    __syncthreads();
    const int eg = t >> 6;           // wave id: 4 edge groups
    const int cb = ch * 64 + lane;   // channel within h
    for (int e = eg; e < 500; e += 4) {
      int pe = epack[e];             // broadcast read
      int s = pe & 255, d = pe >> 8;
      atomicAdd(&sbuf[(d << 6) + lane], h[(s << 8) + cb]);  // ds_add_f32
    }
    __syncthreads();
    for (int i = t; i < 3200; i += 256) {
      int n = i >> 6;
      h[(n << 8) + ch * 64 + (i & 63)] = sbuf[i] * ins_[n];  // in_deg^-0.5
    }
    __syncthreads();
  }

  if (t < 50) war[t] = w_lds[t] * ar_next[t];  // weights for this layer's wm
  __syncthreads();

  // ---- GraphNorm + lrelu + weighted-mean: thread t owns column t ----
  {
    const int c = t;
    float v[50];
    float s1 = 0.f;
#pragma unroll
    for (int n = 0; n < 50; n++) { v[n] = h[(n << 8) + c]; s1 += v[n]; }
    float mean = s1 * 0.02f;
    float am = alpha[c] * mean;
    float s2 = 0.f;
#pragma unroll
    for (int n = 0; n < 50; n++) { float sb = v[n] - am; v[n] = sb; s2 += sb * sb; }
    float gi = gamma[c] * rsqrtf(s2 * 0.02f + EPSQ);
    float bt = beta[c];
    float wm = 0.f;
#pragma unroll
    for (int n = 0; n < 50; n++) {
      float o = lrelu(gi * v[n] + bt);
      h[(n << 8) + c] = o;   // own column: no race
      wm += war[n] * o;
    }
    out[b * 1024 + ro_off + 64 + c] = lrelu(wm * 0.02f);
  }
  __syncthreads();

  // ---- readout MLP1: s1[50,128] = relu(h @ rW1 + b1) ----
  {
    const int col = lane + 64 * jg;  // 128 cols over 2 wave-pairs
    const int r0 = half * 25;
    float acc[25];
#pragma unroll
    for (int i = 0; i < 25; i++) acc[i] = 0.f;
    float w0, w1, w2v, w3;
    { const float* Wp = rW1 + col;
      w0 = Wp[0]; w1 = Wp[128]; w2v = Wp[256]; w3 = Wp[384]; }
    for (int kt = 0; kt < 64; ++kt) {
      const int k = kt * 4;
      const int kn = (kt + 1 < 64) ? (k + 4) : k;
      float n0, n1, n2, n3;
      { const float* Wn = rW1 + kn * 128 + col;
        n0 = Wn[0]; n1 = Wn[128]; n2 = Wn[256]; n3 = Wn[384]; }
#pragma unroll
      for (int i = 0; i < 25; i++) {
        float4 av = *(const float4*)(h + ((r0 + i) << 8) + k);
        acc[i] += av.x * w0 + av.y * w1 + av.z * w2v + av.w * w3;
      }
      w0 = n0; w1 = n1; w2v = n2; w3 = n3;
    }
    float b1v = rb1[col];
#pragma unroll
    for (int i = 0; i < 25; i++)
      sbuf[(r0 + i) * 128 + col] = fmaxf(acc[i] + b1v, 0.f);
  }
  __syncthreads();

  // ---- readout MLP2 partial: [50,128]@[128,64], k split across jg ----
  {
    const int col = lane;
    const int r0 = half * 25;
    float acc[25];
#pragma unroll
    for (int i = 0; i < 25; i++) acc[i] = 0.f;
    for (int kt = 0; kt < 16; ++kt) {
      const int k = jg * 64 + kt * 4;
      const float* Wk = rW2 + k * 64 + col;
      float w0 = Wk[0], w1 = Wk[64], w2v = Wk[128], w3 = Wk[192];
#pragma unroll
      for (int i = 0; i < 25; i++) {
        float4 sv = *(const float4*)(sbuf + (r0 + i) * 128 + k);
        acc[i] += sv.x * w0 + sv.y * w1 + sv.z * w2v + sv.w * w3;
      }
    }
    float p = 0.f;
#pragma unroll
    for (int i = 0; i < 25; i++) p += acc[i];  // row-sum: part of mean over nodes
    red[((half << 1) + jg) * 64 + col] = p;
  }
  __syncthreads();
  if (t < 64) {
    float tot = red[t] + red[64 + t] + red[128 + t] + red[192 + t];
    out[b * 1024 + ro_off + t] = lrelu(tot * 0.02f + rb2[t]);
  }
  __syncthreads();
}

__global__ __launch_bounds__(256)
void gnn_fused(GnnArgs a, float* __restrict__ out) {
  __shared__ alignas(16) float h[50 * 256];     // 51200 B activations
  __shared__ alignas(16) float sbuf[50 * 128];  // 25600 B: xin / agg / mlp-hidden
  __shared__ unsigned short epack[512];         // packed (src | dst<<8)
  __shared__ float w_lds[64];
  __shared__ float war[64];
  __shared__ float outs_[64];
  __shared__ float ins_[64];
  __shared__ float red[256];
  __shared__ int cnt[128];                      // out/in degree counters

  const int t = threadIdx.x;
  const int b = blockIdx.x;
  const int lane = t & 63;
  const int jg = (t >> 6) & 1;
  const int half = t >> 7;

  // P0: zero counters, load x -> sbuf (vectorized), node weights
  if (t < 128) cnt[t] = 0;
  {
    const float4* xg = (const float4*)(a.x + b * 3200);
    float4* sb4 = (float4*)sbuf;
    for (int i = t; i < 800; i += 256) sb4[i] = xg[i];
  }
  if (t < 50) w_lds[t] = a.w[b * 50 + t];
  __syncthreads();

  // P1: pack edges into LDS + degree counting
  {
    const int* srcg = a.src + b * 500;
    const int* dstg = a.dst + b * 500;
    for (int e = t; e < 500; e += 256) {
      int s = srcg[e], d = dstg[e];
      epack[e] = (unsigned short)(s | (d << 8));
      atomicAdd(&cnt[s], 1);
      atomicAdd(&cnt[64 + d], 1);
    }
  }
  if (t < 50) war[t] = w_lds[t] * a.ar[0][t];
  __syncthreads();

  // P2: degree scales + weighted-mean of raw input (part 0)
  if (t < 50) {
    outs_[t] = rsqrtf(fmaxf((float)cnt[t], 1.f));
    ins_[t] = rsqrtf(fmaxf((float)cnt[64 + t], 1.f));
  }
  if (t < 64) {
    float s = 0.f;
#pragma unroll
    for (int n = 0; n < 50; n++) s += war[n] * sbuf[(n << 6) + t];
    out[b * 1024 + t] = lrelu(s * 0.02f);
  }
  // (no barrier needed: conv reads sbuf written in P0; outs_ consumed only
  //  after conv's internal barrier)

  // ---- layer 1 ----
  conv_matmul<64>(sbuf, a.W[0], h, outs_, lane, jg, half);
  post_conv(h, sbuf, epack, ins_, w_lds, war, red, a.ar[1],
            a.gamma[0], a.beta[0], a.alpha[0],
            a.rW1[0], a.rb1[0], a.rW2[0], a.rb2[0],
            out, b, 64, t, lane, jg, half);
  // ---- layer 2 ----
  conv_matmul<256>(h, a.W[1], h, outs_, lane, jg, half);
  post_conv(h, sbuf, epack, ins_, w_lds, war, red, a.ar[2],
            a.gamma[1], a.beta[1], a.alpha[1],
            a.rW1[1], a.rb1[1], a.rW2[1], a.rb2[1],
            out, b, 64 + 320, t, lane, jg, half);
  // ---- layer 3 ----
  conv_matmul<256>(h, a.W[2], h, outs_, lane, jg, half);
  post_conv(h, sbuf, epack, ins_, w_lds, war, red, a.ar[3],
            a.gamma[2], a.beta[2], a.alpha[2],
            a.rW1[2], a.rb1[2], a.rW2[2], a.rb2[2],
            out, b, 64 + 640, t, lane, jg, half);
}

extern "C" void kernel_launch(void* const* d_in, const int* in_sizes, int n_in,
                              void* d_out, int out_size, void* d_ws, size_t ws_size,
                              hipStream_t stream) {
  GnnArgs a;
  a.x = (const float*)d_in[0];
  a.w = (const float*)d_in[1];
  a.src = (const int*)d_in[2];
  a.dst = (const int*)d_in[3];
  a.W[0] = (const float*)d_in[4];
  a.W[1] = (const float*)d_in[5];
  a.W[2] = (const float*)d_in[6];
  a.ar[0] = (const float*)d_in[7];
  a.ar[1] = (const float*)d_in[8];
  a.ar[2] = (const float*)d_in[9];
  a.ar[3] = (const float*)d_in[10];
  for (int l = 0; l < 3; l++) {
    a.gamma[l] = (const float*)d_in[11 + 7 * l];
    a.beta[l]  = (const float*)d_in[12 + 7 * l];
    a.alpha[l] = (const float*)d_in[13 + 7 * l];
    a.rW1[l]   = (const float*)d_in[14 + 7 * l];
    a.rb1[l]   = (const float*)d_in[15 + 7 * l];
    a.rW2[l]   = (const float*)d_in[16 + 7 * l];
    a.rb2[l]   = (const float*)d_in[17 + 7 * l];
  }
  const int B = in_sizes[0] / 3200;  // 2048
  hipLaunchKernelGGL(gnn_fused, dim3(B), dim3(256), 0, stream, a, (float*)d_out);
}

// Round 3
// 858.629 us; speedup vs baseline: 7.9767x; 7.9767x over previous
//
#include <hip/hip_runtime.h>

#define NEG 0.01f

typedef float f32x4 __attribute__((ext_vector_type(4)));
typedef short short8 __attribute__((ext_vector_type(8)));

__device__ __forceinline__ float lrelu(float v) { return v > 0.f ? v : NEG * v; }

// ---- bf16 hi/lo split helpers (bit tricks, RNE) ----
__device__ __forceinline__ unsigned short bf16_rne(float x) {
  unsigned u = __float_as_uint(x);
  unsigned r = u + 0x7fffu + ((u >> 16) & 1u);
  return (unsigned short)(r >> 16);
}
__device__ __forceinline__ float bf16_to_f(unsigned short h) {
  return __uint_as_float(((unsigned)h) << 16);
}

#define MFMA16(a, b, c) __builtin_amdgcn_mfma_f32_16x16x32_bf16(a, b, c, 0, 0, 0)

// =====================================================================
// Prep kernel: build transposed bf16 hi/lo weight planes in workspace.
// WT[n][k] (row-major, K contiguous) from W[k][n].
// ws layout (shorts):
//  0:      w1hi[256*64]   16384: w1lo
//  32768:  w2hi[256*256]  98304: w2lo
//  163840: w3hi           229376: w3lo
//  294912: r1hi[128*256]  327680: r1lo
//  360448: r2hi           393216: r2lo
//  425984: r3hi           458752: r3lo     (total 491520 shorts = 983040 B)
// =====================================================================
__global__ void prep_planes(const float* __restrict__ W1, const float* __restrict__ W2,
                            const float* __restrict__ W3, const float* __restrict__ R1,
                            const float* __restrict__ R2, const float* __restrict__ R3,
                            unsigned short* __restrict__ ws) {
  int idx = blockIdx.x * 256 + threadIdx.x;
  if (idx >= 245760) return;
  const float* src; int K, N; unsigned short *hi, *lo; int e;
  if (idx < 16384)       { src = W1; K = 64;  N = 256; hi = ws;          lo = ws + 16384;  e = idx; }
  else if (idx < 81920)  { src = W2; K = 256; N = 256; hi = ws + 32768;  lo = ws + 98304;  e = idx - 16384; }
  else if (idx < 147456) { src = W3; K = 256; N = 256; hi = ws + 163840; lo = ws + 229376; e = idx - 81920; }
  else if (idx < 180224) { src = R1; K = 256; N = 128; hi = ws + 294912; lo = ws + 327680; e = idx - 147456; }
  else if (idx < 212992) { src = R2; K = 256; N = 128; hi = ws + 360448; lo = ws + 393216; e = idx - 180224; }
  else                   { src = R3; K = 256; N = 128; hi = ws + 425984; lo = ws + 458752; e = idx - 212992; }
  int n = e / K, k = e - n * K;
  float v = src[k * N + n];
  unsigned short hb = bf16_rne(v);
  hi[e] = hb;
  lo[e] = bf16_rne(v - bf16_to_f(hb));
}

// =====================================================================
// Conv GEMM via MFMA: C[50(→64),256] = A[50,KK] @ W[KK,256], 3-term bf16 split.
// 8 waves; wave w covers cols [w*32, w*32+32) (2 N-tiles), all 4 M-tiles.
// A planes in LDS, [row][K] bf16, row stride 512 B, XOR-swizzle byte^=((row&7)<<4).
// Rows >= 50 read junk (in-bounds) -> junk C rows, masked at write-out.
// =====================================================================
template <int KK>
__device__ __forceinline__ void conv_mfma(const char* AhiB, const char* AloB,
                                          const unsigned short* __restrict__ Whi,
                                          const unsigned short* __restrict__ Wlo,
                                          f32x4 acc[4][2], int w, int l) {
  const int g = l >> 4, r15 = l & 15;
  const int aswz = (l & 7) << 4;
  const int arow = r15 << 9;
  const int colA = w * 32 + r15;
#pragma unroll
  for (int kt = 0; kt < KK / 32; ++kt) {
    const int ka = (kt * 64 + g * 16) ^ aswz;
    const int ke = kt * 32 + g * 8;
    short8 ah[4], al[4];
#pragma unroll
    for (int mt = 0; mt < 4; ++mt) {
      ah[mt] = *(const short8*)(AhiB + (mt * 8192 + arow + ka));
      al[mt] = *(const short8*)(AloB + (mt * 8192 + arow + ka));
    }
#pragma unroll
    for (int nt = 0; nt < 2; ++nt) {
      const int wc = colA + nt * 16;
      short8 bh = *(const short8*)(Whi + (size_t)wc * KK + ke);
      short8 bl = *(const short8*)(Wlo + (size_t)wc * KK + ke);
#pragma unroll
      for (int mt = 0; mt < 4; ++mt) {
        acc[mt][nt] = MFMA16(ah[mt], bh, acc[mt][nt]);
        acc[mt][nt] = MFMA16(al[mt], bh, acc[mt][nt]);
        acc[mt][nt] = MFMA16(ah[mt], bl, acc[mt][nt]);
      }
    }
  }
}

// MLP1 via MFMA + fused relu + column-sum over nodes (mean commutes with MLP2).
__device__ __forceinline__ void mlp1_mfma(const char* AhiB, const char* AloB,
                                          const unsigned short* __restrict__ Whi,
                                          const unsigned short* __restrict__ Wlo,
                                          const float* __restrict__ b1, float* s1sum,
                                          int w, int l) {
  const int g = l >> 4, r15 = l & 15;
  const int aswz = (l & 7) << 4;
  const int arow = r15 << 9;
  const int col = w * 16 + r15;
  f32x4 acc[4] = {};
#pragma unroll
  for (int kt = 0; kt < 8; ++kt) {
    const int ka = (kt * 64 + g * 16) ^ aswz;
    const int ke = kt * 32 + g * 8;
    short8 bh = *(const short8*)(Whi + (size_t)col * 256 + ke);
    short8 bl = *(const short8*)(Wlo + (size_t)col * 256 + ke);
#pragma unroll
    for (int mt = 0; mt < 4; ++mt) {
      short8 ah = *(const short8*)(AhiB + (mt * 8192 + arow + ka));
      short8 al = *(const short8*)(AloB + (mt * 8192 + arow + ka));
      acc[mt] = MFMA16(ah, bh, acc[mt]);
      acc[mt] = MFMA16(al, bh, acc[mt]);
      acc[mt] = MFMA16(ah, bl, acc[mt]);
    }
  }
  const float b1v = b1[col];
  float colsum = 0.f;
#pragma unroll
  for (int mt = 0; mt < 4; ++mt)
#pragma unroll
    for (int r = 0; r < 4; ++r) {
      float v = fmaxf(acc[mt][r] + b1v, 0.f);
      if (mt < 3) colsum += v;                  // rows < 48 always valid
      else if (g == 0 && r < 2) colsum += v;    // rows 48,49
    }
  colsum += __shfl_xor(colsum, 16);
  colsum += __shfl_xor(colsum, 32);
  if (l < 16) s1sum[w * 16 + l] = colsum;
}

struct GnnArgs {
  const float* x;  const float* w;  const int* src;  const int* dst;
  const float* ar[4];
  const float* gamma[3]; const float* beta[3]; const float* alpha[3];
  const float* rb1[3]; const float* rW2[3]; const float* rb2[3];
  const unsigned short* whi[3]; const unsigned short* wlo[3];
  const unsigned short* rhi[3]; const unsigned short* rlo[3];
};

// Per-layer: conv(MFMA) -> 4x{Cwrite|gather|stats|apply} -> MLP1(MFMA) -> outputs
template <int KK>
__device__ __forceinline__ void do_layer(
    char* AhiB, char* AloB, float* Cchunk, float* agg,
    const unsigned short* csr_s, const int* rs,
    const float* w_lds, float* war, const float* outs_, const float* ins_,
    float* statsS1, float* statsS2, float* wmacc, float* s1sum,
    const unsigned short* Whi, const unsigned short* Wlo,
    const unsigned short* Rhi, const unsigned short* Rlo,
    const float* gamma, const float* beta, const float* alpha,
    const float* ar_next, const float* b1, const float* rW2f, const float* b2,
    float* out, int b, int ro_off, int t, int w, int l) {
  f32x4 acc[4][2] = {};
  conv_mfma<KK>(AhiB, AloB, Whi, Wlo, acc, w, l);

  const int g = l >> 4, r15 = l & 15;
#pragma unroll 1
  for (int ch = 0; ch < 4; ++ch) {
    __syncthreads();  // prev apply done / wm read done
    if (t < 64) statsS1[t] = 0.f;
    else if (t < 128) statsS2[t - 64] = 0.f;
    if (ch == 0) {
      if (t < 256) wmacc[t] = 0.f;
      if (t < 50) war[t] = w_lds[t] * ar_next[t];
    }
    if ((w >> 1) == ch) {  // stage this chunk's C cols (scaled by outdeg^-0.5)
      const int cb = (w & 1) * 32;
#pragma unroll
      for (int mt = 0; mt < 4; ++mt)
#pragma unroll
        for (int nt = 0; nt < 2; ++nt)
#pragma unroll
          for (int r = 0; r < 4; ++r) {
            int row = mt * 16 + g * 4 + r;
            if (row < 50)
              Cchunk[row * 64 + cb + nt * 16 + r15] = acc[mt][nt][r] * outs_[row];
          }
    }
    __syncthreads();
    {  // CSR gather (no atomics): wave w sums in-edges of nodes w, w+8, ...
      const int lo2 = l & 31, hf = l >> 5;
      for (int d = w; d < 50; d += 8) {
        float ax = 0.f, ay = 0.f;
        const int e1 = rs[d + 1];
        for (int e = rs[d] + hf; e < e1; e += 2) {
          int s = csr_s[e];
          const float2 cv = *(const float2*)&Cchunk[s * 64 + lo2 * 2];
          ax += cv.x; ay += cv.y;
        }
        ax += __shfl_xor(ax, 32);
        ay += __shfl_xor(ay, 32);
        if (hf == 0) { agg[d * 64 + lo2 * 2] = ax; agg[d * 64 + lo2 * 2 + 1] = ay; }
      }
    }
    __syncthreads();
    {  // per-channel stats over nodes (indeg scale folded in)
      const int c = t & 63;
      float s1 = 0.f, s2 = 0.f;
      for (int j = 0; j < 7; ++j) {
        int n = (t >> 6) + 8 * j;
        if (n < 50) { float v = agg[n * 64 + c] * ins_[n]; s1 += v; s2 += v * v; }
      }
      atomicAdd(&statsS1[c], s1);
      atomicAdd(&statsS2[c], s2);
    }
    __syncthreads();
    {  // GraphNorm + lrelu + bf16 hi/lo plane write + weighted-mean partials
      const int c = t & 63, colg = ch * 64 + c;
      const float m = statsS1[c] * 0.02f;
      const float am = alpha[colg] * m;
      const float varr = statsS2[c] * 0.02f - am * (2.f * m - am);
      const float gi = gamma[colg] * rsqrtf(fmaxf(varr, 0.f) + 1e-5f);
      const float be = beta[colg];
      float wmp = 0.f;
      for (int j = 0; j < 7; ++j) {
        int n = (t >> 6) + 8 * j;
        if (n < 50) {
          float v = agg[n * 64 + c] * ins_[n];
          float o = (v - am) * gi + be;
          o = o > 0.f ? o : NEG * o;
          wmp += war[n] * o;
          unsigned short hb = bf16_rne(o);
          float resid = o - bf16_to_f(hb);
          int bo = (n * 512 + 2 * colg) ^ ((n & 7) << 4);
          *(unsigned short*)(AhiB + bo) = hb;
          *(unsigned short*)(AloB + bo) = bf16_rne(resid);
        }
      }
      atomicAdd(&wmacc[colg], wmp);
    }
  }
  __syncthreads();  // planes (new h) complete
  mlp1_mfma(AhiB, AloB, Rhi, Rlo, b1, s1sum, w, l);
  __syncthreads();
  if (t < 64) {  // MLP2 on node-mean of s1 (mean commutes with linear layer)
    float a = 0.f;
    for (int k = 0; k < 128; ++k) a += s1sum[k] * rW2f[k * 64 + t];
    a = a * 0.02f + b2[t];
    out[b * 1024 + ro_off + t] = lrelu(a);
  }
  if (t < 256) out[b * 1024 + ro_off + 64 + t] = lrelu(wmacc[t] * 0.02f);
}

__global__ __launch_bounds__(512, 4) void gnn_fused(GnnArgs a, float* __restrict__ out) {
  // Big buffers carved from one block so A-plane junk-row overreads (rows 50..63,
  // up to byte 58367) stay provably inside the allocation.
  __shared__ alignas(16) char bigb[76800];
  char* AhiB   = bigb;                      // 25600 B bf16 hi plane [50][256]
  char* AloB   = bigb + 25600;              // 25600 B bf16 lo plane
  float* Cchunk = (float*)(bigb + 51200);   // 12800 B [50][64] f32
  float* agg    = (float*)(bigb + 64000);   // 12800 B [50][64] f32
  __shared__ alignas(16) char smallb[4864];
  unsigned short* csr_s = (unsigned short*)smallb;      // 1024
  int*   rs      = (int*)(smallb + 1024);               // 256 (51 used)
  int*   cnt     = (int*)(smallb + 1280);               // 512 (out 0..63, in 64..127)
  float* w_lds   = (float*)(smallb + 1792);
  float* war     = (float*)(smallb + 2048);
  float* outs_   = (float*)(smallb + 2304);
  float* ins_    = (float*)(smallb + 2560);
  float* statsS1 = (float*)(smallb + 2816);
  float* statsS2 = (float*)(smallb + 3072);
  float* wmacc   = (float*)(smallb + 3328);             // 1024
  float* s1sum   = (float*)(smallb + 4352);             // 512
  int* fillp = (int*)statsS1;  // prologue-only alias

  const int t = threadIdx.x, b = blockIdx.x;
  const int l = t & 63, w = t >> 6;

  // ---- prologue: degrees, CSR build, x -> bf16 planes, weighted-mean part 0 ----
  if (t < 128) cnt[t] = 0;
  if (t < 64) fillp[t] = 0;
  if (t < 256) wmacc[t] = 0.f;
  if (t < 50) w_lds[t] = a.w[b * 50 + t];
  __syncthreads();
  int es = 0, ed = 0;
  if (t < 500) {
    es = a.src[b * 500 + t];
    ed = a.dst[b * 500 + t];
    atomicAdd(&cnt[es], 1);
    atomicAdd(&cnt[64 + ed], 1);
  }
  __syncthreads();
  if (t < 50) {
    outs_[t] = rsqrtf(fmaxf((float)cnt[t], 1.f));
    ins_[t]  = rsqrtf(fmaxf((float)cnt[64 + t], 1.f));
    war[t] = w_lds[t] * a.ar[0][t];
  }
  if (t == 0) {
    int run = 0;
    for (int n = 0; n < 50; ++n) { rs[n] = run; run += cnt[64 + n]; }
    rs[50] = run;
  }
  __syncthreads();
  if (t < 500) {
    int pos = rs[ed] + atomicAdd(&fillp[ed], 1);
    csr_s[pos] = (unsigned short)es;
  }
  {  // x load -> hi/lo planes (cols 0..63) + part-0 weighted mean
    const int c = t & 63;
    float wmp = 0.f;
    for (int j = 0; j < 7; ++j) {
      int n = (t >> 6) + 8 * j;
      if (n < 50) {
        float v = a.x[b * 3200 + n * 64 + c];
        wmp += war[n] * v;
        unsigned short hb = bf16_rne(v);
        float resid = v - bf16_to_f(hb);
        int bo = (n * 512 + 2 * c) ^ ((n & 7) << 4);
        *(unsigned short*)(AhiB + bo) = hb;
        *(unsigned short*)(AloB + bo) = bf16_rne(resid);
      }
    }
    atomicAdd(&wmacc[c], wmp);
  }
  __syncthreads();
  if (t < 64) out[b * 1024 + t] = lrelu(wmacc[t] * 0.02f);
  // (wmacc re-zeroed after the next barrier inside do_layer chunk 0)

  do_layer<64>(AhiB, AloB, Cchunk, agg, csr_s, rs, w_lds, war, outs_, ins_,
               statsS1, statsS2, wmacc, s1sum,
               a.whi[0], a.wlo[0], a.rhi[0], a.rlo[0],
               a.gamma[0], a.beta[0], a.alpha[0], a.ar[1],
               a.rb1[0], a.rW2[0], a.rb2[0], out, b, 64, t, w, l);
  do_layer<256>(AhiB, AloB, Cchunk, agg, csr_s, rs, w_lds, war, outs_, ins_,
                statsS1, statsS2, wmacc, s1sum,
                a.whi[1], a.wlo[1], a.rhi[1], a.rlo[1],
                a.gamma[1], a.beta[1], a.alpha[1], a.ar[2],
                a.rb1[1], a.rW2[1], a.rb2[1], out, b, 384, t, w, l);
  do_layer<256>(AhiB, AloB, Cchunk, agg, csr_s, rs, w_lds, war, outs_, ins_,
                statsS1, statsS2, wmacc, s1sum,
                a.whi[2], a.wlo[2], a.rhi[2], a.rlo[2],
                a.gamma[2], a.beta[2], a.alpha[2], a.ar[3],
                a.rb1[2], a.rW2[2], a.rb2[2], out, b, 704, t, w, l);
}

extern "C" void kernel_launch(void* const* d_in, const int* in_sizes, int n_in,
                              void* d_out, int out_size, void* d_ws, size_t ws_size,
                              hipStream_t stream) {
  const float* W1 = (const float*)d_in[4];
  const float* W2 = (const float*)d_in[5];
  const float* W3 = (const float*)d_in[6];
  const float* R1 = (const float*)d_in[14];
  const float* R2 = (const float*)d_in[21];
  const float* R3 = (const float*)d_in[28];
  unsigned short* ws = (unsigned short*)d_ws;

  hipLaunchKernelGGL(prep_planes, dim3(960), dim3(256), 0, stream,
                     W1, W2, W3, R1, R2, R3, ws);

  GnnArgs a;
  a.x = (const float*)d_in[0];
  a.w = (const float*)d_in[1];
  a.src = (const int*)d_in[2];
  a.dst = (const int*)d_in[3];
  a.ar[0] = (const float*)d_in[7];
  a.ar[1] = (const float*)d_in[8];
  a.ar[2] = (const float*)d_in[9];
  a.ar[3] = (const float*)d_in[10];
  for (int i = 0; i < 3; ++i) {
    a.gamma[i] = (const float*)d_in[11 + 7 * i];
    a.beta[i]  = (const float*)d_in[12 + 7 * i];
    a.alpha[i] = (const float*)d_in[13 + 7 * i];
    a.rb1[i]   = (const float*)d_in[15 + 7 * i];
    a.rW2[i]   = (const float*)d_in[16 + 7 * i];
    a.rb2[i]   = (const float*)d_in[17 + 7 * i];
  }
  a.whi[0] = ws;          a.wlo[0] = ws + 16384;
  a.whi[1] = ws + 32768;  a.wlo[1] = ws + 98304;
  a.whi[2] = ws + 163840; a.wlo[2] = ws + 229376;
  a.rhi[0] = ws + 294912; a.rlo[0] = ws + 327680;
  a.rhi[1] = ws + 360448; a.rlo[1] = ws + 393216;
  a.rhi[2] = ws + 425984; a.rlo[2] = ws + 458752;

  const int B = in_sizes[0] / 3200;
  hipLaunchKernelGGL(gnn_fused, dim3(B), dim3(512), 0, stream, a, (float*)d_out);
}